// Round 4
// baseline (366.056 us; speedup 1.0000x reference)
//
#include <hip/hip_runtime.h>
#include <hip/hip_bf16.h>
#include <math.h>

#define IN_CHN 128
#define OUT_CHN 128
#define KD 192
#define TM 64                  // edges per tile

typedef __bf16 bf16x8 __attribute__((ext_vector_type(8)));
typedef float f32x4 __attribute__((ext_vector_type(4)));

static __device__ __forceinline__ unsigned short f2b(float f) {
    return __builtin_bit_cast(unsigned short, (__bf16)f);   // RNE
}
static __device__ __forceinline__ float b2f(unsigned short b) {
    return __uint_as_float(((unsigned int)b) << 16);
}
static __device__ __forceinline__ float fast_tanh(float x) {
    float e = __expf(2.0f * x);
    return 1.0f - 2.0f * __builtin_amdgcn_rcpf(e + 1.0f);
}

// ---------------- x -> bf16 pre-conversion ----------------

__global__ __launch_bounds__(256) void cvt_x(const float* __restrict__ x,
    unsigned short* __restrict__ xb, long long n8)
{
    long long i = (long long)blockIdx.x * 256 + threadIdx.x;
    if (i >= n8) return;
    const float4* src = (const float4*)(x + i * 8);
    float4 v0 = src[0], v1 = src[1];
    ushort4 p0 = { f2b(v0.x), f2b(v0.y), f2b(v0.z), f2b(v0.w) };
    ushort4 p1 = { f2b(v1.x), f2b(v1.y), f2b(v1.z), f2b(v1.w) };
    *(ushort4*)(xb + i * 8)     = p0;
    *(ushort4*)(xb + i * 8 + 4) = p1;
}

// ---------------- CSR build ----------------

__global__ __launch_bounds__(256) void zero_deg(int* deg, int n) {
    int i = blockIdx.x * 256 + threadIdx.x;
    if (i < n) deg[i] = 0;
}

__global__ __launch_bounds__(256) void count_deg(const int* __restrict__ ei,
                                                 int* __restrict__ deg, int E) {
    int e = blockIdx.x * 256 + threadIdx.x;
    if (e < E) atomicAdd(&deg[ei[E + e]], 1);
}

static __device__ __forceinline__ int wave_incl_scan(int v, int lane) {
    #pragma unroll
    for (int off = 1; off < 64; off <<= 1) {
        int t = __shfl_up(v, off);
        if (lane >= off) v += t;
    }
    return v;
}

__global__ __launch_bounds__(256) void scan_local(const int* __restrict__ deg,
    int* __restrict__ offs, int* __restrict__ partial, int Nn)
{
    __shared__ int wsum[4];
    int tid = threadIdx.x, lane = tid & 63, wid = tid >> 6;
    int i = blockIdx.x * 256 + tid;
    int v = (i < Nn) ? deg[i] : 0;
    int incl = wave_incl_scan(v, lane);
    if (lane == 63) wsum[wid] = incl;
    __syncthreads();
    int wpre = 0;
    for (int w = 0; w < wid; ++w) wpre += wsum[w];
    if (i < Nn) offs[i] = wpre + incl - v;
    if (tid == 255) partial[blockIdx.x] = wpre + incl;
}

__global__ __launch_bounds__(256) void scan_partial(int* __restrict__ partial, int nparts)
{
    __shared__ int wsum[4];
    int tid = threadIdx.x, lane = tid & 63, wid = tid >> 6;
    int v = (tid < nparts) ? partial[tid] : 0;
    int incl = wave_incl_scan(v, lane);
    if (lane == 63) wsum[wid] = incl;
    __syncthreads();
    int wpre = 0;
    for (int w = 0; w < wid; ++w) wpre += wsum[w];
    if (tid < nparts) partial[tid] = wpre + incl - v;
}

__global__ __launch_bounds__(256) void finalize_offs(int* __restrict__ offs,
    const int* __restrict__ partial, int* __restrict__ cursor, int Nn)
{
    int i = blockIdx.x * 256 + threadIdx.x;
    if (i < Nn) { int o = offs[i] + partial[i >> 8]; offs[i] = o; cursor[i] = o; }
}

__global__ __launch_bounds__(256) void fill_perm(const int* __restrict__ ei,
    const float* __restrict__ et, int* __restrict__ cursor,
    int* __restrict__ srcp, float* __restrict__ etp, int E)
{
    int e = blockIdx.x * 256 + threadIdx.x;
    if (e < E) {
        int d = ei[E + e];
        int pos = atomicAdd(&cursor[d], 1);
        srcp[pos] = ei[e];
        etp[pos] = et[e];
    }
}

// ---------------- MFMA GEMM + alpha (no LDS data path) ----------------
// h = tanh([x[src], te(t)] @ W^T + b), alpha = h . attn, edges in CSR order.
// Per block: 4 waves; tile = 64 edges x 128 ch; W frags in registers;
// A-frags gathered directly from bf16 xb; te frags computed in-register.
// MFMA D (W as A-operand): row = channel, col = edge (lane&15).

__global__ __launch_bounds__(256) void gemm_mfma(
    const unsigned short* __restrict__ xb, const int* __restrict__ srcp,
    const float* __restrict__ etp, const float* __restrict__ freqs,
    const float* __restrict__ lw, const float* __restrict__ lb,
    const float* __restrict__ attn,
    unsigned short* __restrict__ h_p, float* __restrict__ alpha_p,
    int E, int n_tiles)
{
    __shared__ float apart[2][4][64];   // [buf][wave][edge] alpha partials

    const int tid  = threadIdx.x;
    const int lane = tid & 63;
    const int wv   = tid >> 6;          // wave 0..3
    const int c16  = lane & 15;
    const int g    = lane >> 4;         // 0..3
    const int wbase = wv * 32;          // this wave's channel base

    // W fragments, persistent in registers: Wf[kk][nf]
    // lane's row(ch) = wbase + nf*16 + c16 ; k = kk*32 + g*8 + j
    bf16x8 Wf[6][2];
    #pragma unroll
    for (int kk = 0; kk < 6; ++kk)
        #pragma unroll
        for (int nf = 0; nf < 2; ++nf) {
            const float* wp = lw + (size_t)(wbase + nf * 16 + c16) * KD + kk * 32 + g * 8;
            float4 v0 = *(const float4*)wp;
            float4 v1 = *(const float4*)(wp + 4);
            bf16x8 b;
            b[0] = (__bf16)v0.x; b[1] = (__bf16)v0.y; b[2] = (__bf16)v0.z; b[3] = (__bf16)v0.w;
            b[4] = (__bf16)v1.x; b[5] = (__bf16)v1.y; b[6] = (__bf16)v1.z; b[7] = (__bf16)v1.w;
            Wf[kk][nf] = b;
        }

    // bias/attn for this lane's output channels: wbase + nf*16 + g*4 + r
    f32x4 bias_v[2], attn_v[2];
    #pragma unroll
    for (int nf = 0; nf < 2; ++nf) {
        bias_v[nf] = *(const f32x4*)(lb   + wbase + nf * 16 + g * 4);
        attn_v[nf] = *(const f32x4*)(attn + wbase + nf * 16 + g * 4);
    }

    // this lane's 8 frequencies (pre-scaled by 2*pi); v_sin takes revolutions
    float frv[8];
    #pragma unroll
    for (int j = 0; j < 8; ++j) frv[j] = freqs[g * 8 + j] * 6.283185307179586f;

    int cur = 0;
    for (int tile = blockIdx.x; tile < n_tiles; tile += gridDim.x) {
        const int e0 = tile * TM;

        // per-mi edge metadata (4 lanes share an address -> merged load)
        int sv[4]; float tv[4];
        #pragma unroll
        for (int mi = 0; mi < 4; ++mi) {
            int e  = e0 + mi * 16 + c16;
            int ec = e < E ? e : E - 1;
            sv[mi] = srcp[ec];
            tv[mi] = etp[ec];
        }

        f32x4 acc[4][2];
        #pragma unroll
        for (int mi = 0; mi < 4; ++mi) {
            acc[mi][0] = (f32x4){0.f, 0.f, 0.f, 0.f};
            acc[mi][1] = (f32x4){0.f, 0.f, 0.f, 0.f};
        }

        #pragma unroll
        for (int mi = 0; mi < 4; ++mi) {
            const uint4* xr = (const uint4*)(xb + (size_t)sv[mi] * IN_CHN + g * 8);
            #pragma unroll
            for (int kk = 0; kk < 4; ++kk) {
                bf16x8 a = __builtin_bit_cast(bf16x8, xr[kk * 4]);
                acc[mi][0] = __builtin_amdgcn_mfma_f32_16x16x32_bf16(Wf[kk][0], a, acc[mi][0], 0, 0, 0);
                acc[mi][1] = __builtin_amdgcn_mfma_f32_16x16x32_bf16(Wf[kk][1], a, acc[mi][1], 0, 0, 0);
            }
            // time-encoding frags: k = 128 + g*8 + j (sin), 160 + g*8 + j (cos)
            bf16x8 s8, c8;
            #pragma unroll
            for (int j = 0; j < 8; ++j) {
                float rev = tv[mi] * frv[j] * 0.15915494309189535f;  // revolutions
                float fr  = rev - floorf(rev);
                s8[j] = (__bf16)__sinf(fr * 6.283185307179586f);
                c8[j] = (__bf16)__cosf(fr * 6.283185307179586f);
            }
            acc[mi][0] = __builtin_amdgcn_mfma_f32_16x16x32_bf16(Wf[4][0], s8, acc[mi][0], 0, 0, 0);
            acc[mi][1] = __builtin_amdgcn_mfma_f32_16x16x32_bf16(Wf[4][1], s8, acc[mi][1], 0, 0, 0);
            acc[mi][0] = __builtin_amdgcn_mfma_f32_16x16x32_bf16(Wf[5][0], c8, acc[mi][0], 0, 0, 0);
            acc[mi][1] = __builtin_amdgcn_mfma_f32_16x16x32_bf16(Wf[5][1], c8, acc[mi][1], 0, 0, 0);
        }

        // ---- epilogue: tanh, alpha partial, direct global h store ----
        #pragma unroll
        for (int mi = 0; mi < 4; ++mi) {
            int e = e0 + mi * 16 + c16;
            float p = 0.0f;
            ushort4 pv[2];
            #pragma unroll
            for (int nf = 0; nf < 2; ++nf) {
                f32x4 z = acc[mi][nf];
                #pragma unroll
                for (int r = 0; r < 4; ++r) {
                    float h = fast_tanh(z[r] + bias_v[nf][r]);
                    z[r] = h;
                    p = fmaf(h, attn_v[nf][r], p);
                }
                pv[nf] = (ushort4){ f2b(z[0]), f2b(z[1]), f2b(z[2]), f2b(z[3]) };
            }
            p += __shfl_xor(p, 16);
            p += __shfl_xor(p, 32);
            if (e < E) {
                unsigned short* hp = h_p + (size_t)e * OUT_CHN + wbase + g * 4;
                *(ushort4*)hp        = pv[0];
                *(ushort4*)(hp + 16) = pv[1];
            }
            if (g == 0) apart[cur][wv][mi * 16 + c16] = p;
        }
        __syncthreads();
        if (tid < TM) {
            int e = e0 + tid;
            if (e < E)
                alpha_p[e] = apart[cur][0][tid] + apart[cur][1][tid]
                           + apart[cur][2][tid] + apart[cur][3][tid];
        }
        cur ^= 1;
    }
}

// ---------------- per-node aggregation (one wave per node) ----------------

__global__ __launch_bounds__(256) void agg(
    const unsigned short* __restrict__ h_p, const float* __restrict__ alpha_p,
    const int* __restrict__ offs, const int* __restrict__ deg,
    float* __restrict__ out, int Nn)
{
    int wid  = threadIdx.x >> 6;
    int lane = threadIdx.x & 63;
    int node = blockIdx.x * 4 + wid;
    if (node >= Nn) return;
    int start = offs[node];
    int d = deg[node];
    float* op = out + (size_t)node * OUT_CHN + lane * 2;
    if (d == 0) { op[0] = 0.0f; op[1] = 0.0f; return; }

    float m = -INFINITY;
    for (int i = lane; i < d; i += 64) m = fmaxf(m, alpha_p[start + i]);
    #pragma unroll
    for (int off = 32; off > 0; off >>= 1) m = fmaxf(m, __shfl_xor(m, off));

    float s = 0.0f;
    for (int i = lane; i < d; i += 64) s += __expf(alpha_p[start + i] - m);
    #pragma unroll
    for (int off = 32; off > 0; off >>= 1) s += __shfl_xor(s, off);
    float rs = __builtin_amdgcn_rcpf(s + 1e-16f);

    float a0 = 0.0f, a1 = 0.0f;
    for (int i = 0; i < d; ++i) {
        float w = __expf(alpha_p[start + i] - m) * rs;
        unsigned int hv = *(const unsigned int*)(h_p + (size_t)(start + i) * OUT_CHN + lane * 2);
        a0 = fmaf(b2f((unsigned short)(hv & 0xFFFFu)), w, a0);
        a1 = fmaf(b2f((unsigned short)(hv >> 16)), w, a1);
    }
    op[0] = a0; op[1] = a1;
}

// ---------------- launch ----------------

extern "C" void kernel_launch(void* const* d_in, const int* in_sizes, int n_in,
                              void* d_out, int out_size, void* d_ws, size_t ws_size,
                              hipStream_t stream) {
    const float* x     = (const float*)d_in[0];
    const int*   ei    = (const int*)d_in[1];     // [2, E]
    const float* et    = (const float*)d_in[2];
    const float* freqs = (const float*)d_in[3];
    const float* lw    = (const float*)d_in[4];   // [128, 192]
    const float* lb    = (const float*)d_in[5];
    const float* attn  = (const float*)d_in[6];
    float* out = (float*)d_out;

    const int E  = in_sizes[2];
    const int Nn = in_sizes[0] / IN_CHN;

    // workspace layout
    char* ws = (char*)d_ws;
    unsigned short* h_p = (unsigned short*)ws;                // E*128 bf16 (perm order)
    size_t off = (size_t)E * OUT_CHN * sizeof(unsigned short);
    float* alpha_p = (float*)(ws + off); off += (size_t)E * sizeof(float);
    int*   srcp    = (int*)(ws + off);   off += (size_t)E * sizeof(int);
    float* etp     = (float*)(ws + off); off += (size_t)E * sizeof(float);
    unsigned short* xb = (unsigned short*)(ws + off); off += (size_t)Nn * IN_CHN * sizeof(unsigned short);
    int*   deg     = (int*)(ws + off);   off += (size_t)Nn * sizeof(int);
    int*   offs    = (int*)(ws + off);   off += (size_t)Nn * sizeof(int);
    int*   cursor  = (int*)(ws + off);   off += (size_t)Nn * sizeof(int);
    int*   partial = (int*)(ws + off);

    const int nblk = (Nn + 255) / 256;
    const int eblk = (E + 255) / 256;

    // x -> bf16 (8 elems/thread)
    long long n8 = (long long)Nn * IN_CHN / 8;
    cvt_x<<<(unsigned)((n8 + 255) / 256), 256, 0, stream>>>(x, xb, n8);

    zero_deg<<<nblk, 256, 0, stream>>>(deg, Nn);
    count_deg<<<eblk, 256, 0, stream>>>(ei, deg, E);
    scan_local<<<nblk, 256, 0, stream>>>(deg, offs, partial, Nn);
    scan_partial<<<1, 256, 0, stream>>>(partial, nblk);
    finalize_offs<<<nblk, 256, 0, stream>>>(offs, partial, cursor, Nn);
    fill_perm<<<eblk, 256, 0, stream>>>(ei, et, cursor, srcp, etp, E);

    const int n_tiles = (E + TM - 1) / TM;
    gemm_mfma<<<1024, 256, 0, stream>>>(xb, srcp, etp, freqs, lw, lb, attn,
                                        h_p, alpha_p, E, n_tiles);

    agg<<<(Nn + 3) / 4, 256, 0, stream>>>(h_p, alpha_p, offs, deg, out, Nn);
}

// Round 5
// 310.953 us; speedup vs baseline: 1.1772x; 1.1772x over previous
//
#include <hip/hip_runtime.h>
#include <hip/hip_bf16.h>
#include <math.h>

#define IN_CHN 128
#define OUT_CHN 128
#define KD 192
#define TM 64                  // edges per tile

typedef __bf16 bf16x8 __attribute__((ext_vector_type(8)));
typedef float f32x4 __attribute__((ext_vector_type(4)));

static __device__ __forceinline__ unsigned short f2b(float f) {
    return __builtin_bit_cast(unsigned short, (__bf16)f);   // RNE
}
static __device__ __forceinline__ float b2f(unsigned short b) {
    return __uint_as_float(((unsigned int)b) << 16);
}
static __device__ __forceinline__ float fast_tanh(float x) {
    float e = __expf(2.0f * x);
    return 1.0f - 2.0f * __builtin_amdgcn_rcpf(e + 1.0f);
}

// ---------------- x -> bf16 pre-conversion ----------------

__global__ __launch_bounds__(256) void cvt_x(const float* __restrict__ x,
    unsigned short* __restrict__ xb, long long n8)
{
    long long i = (long long)blockIdx.x * 256 + threadIdx.x;
    if (i >= n8) return;
    const float4* src = (const float4*)(x + i * 8);
    float4 v0 = src[0], v1 = src[1];
    ushort4 p0 = { f2b(v0.x), f2b(v0.y), f2b(v0.z), f2b(v0.w) };
    ushort4 p1 = { f2b(v1.x), f2b(v1.y), f2b(v1.z), f2b(v1.w) };
    *(ushort4*)(xb + i * 8)     = p0;
    *(ushort4*)(xb + i * 8 + 4) = p1;
}

// ---------------- CSR build ----------------

__global__ __launch_bounds__(256) void count_deg(const int* __restrict__ ei,
                                                 int* __restrict__ deg, int E) {
    int e = blockIdx.x * 256 + threadIdx.x;
    if (e < E) atomicAdd(&deg[ei[E + e]], 1);
}

static __device__ __forceinline__ int wave_incl_scan(int v, int lane) {
    #pragma unroll
    for (int off = 1; off < 64; off <<= 1) {
        int t = __shfl_up(v, off);
        if (lane >= off) v += t;
    }
    return v;
}

__global__ __launch_bounds__(256) void scan_local(const int* __restrict__ deg,
    int* __restrict__ offs, int* __restrict__ partial, int Nn)
{
    __shared__ int wsum[4];
    int tid = threadIdx.x, lane = tid & 63, wid = tid >> 6;
    int i = blockIdx.x * 256 + tid;
    int v = (i < Nn) ? deg[i] : 0;
    int incl = wave_incl_scan(v, lane);
    if (lane == 63) wsum[wid] = incl;
    __syncthreads();
    int wpre = 0;
    for (int w = 0; w < wid; ++w) wpre += wsum[w];
    if (i < Nn) offs[i] = wpre + incl - v;
    if (tid == 255) partial[blockIdx.x] = wpre + incl;
}

__global__ __launch_bounds__(256) void scan_partial(int* __restrict__ partial, int nparts)
{
    __shared__ int wsum[4];
    int tid = threadIdx.x, lane = tid & 63, wid = tid >> 6;
    int v = (tid < nparts) ? partial[tid] : 0;
    int incl = wave_incl_scan(v, lane);
    if (lane == 63) wsum[wid] = incl;
    __syncthreads();
    int wpre = 0;
    for (int w = 0; w < wid; ++w) wpre += wsum[w];
    if (tid < nparts) partial[tid] = wpre + incl - v;
}

__global__ __launch_bounds__(256) void finalize_offs(int* __restrict__ offs,
    const int* __restrict__ partial, int* __restrict__ cursor, int Nn)
{
    int i = blockIdx.x * 256 + threadIdx.x;
    if (i < Nn) { int o = offs[i] + partial[i >> 8]; offs[i] = o; cursor[i] = o; }
}

__global__ __launch_bounds__(256) void fill_perm(const int* __restrict__ ei,
    const float* __restrict__ et, int* __restrict__ cursor,
    int* __restrict__ srcp, float* __restrict__ etp, int E)
{
    int e = blockIdx.x * 256 + threadIdx.x;
    if (e < E) {
        int d = ei[E + e];
        int pos = atomicAdd(&cursor[d], 1);
        srcp[pos] = ei[e];
        etp[pos] = et[e];
    }
}

// ---------------- MFMA GEMM + alpha ----------------
// h = tanh([x[src], te(t)] @ W^T + b), alpha = h . attn, edges in CSR order.
// 4 waves/block; tile = 64 edges x 128 ch; W frags in registers; x B-frags
// gathered per-lane from bf16 xb (L1 absorbs cross-wave reuse); te computed
// cooperatively once per tile into swizzled double-buffered LDS (granule
// index XOR row&7 -> 2-way banks = free). One barrier per tile; alpha
// store pipelined one tile behind.

__global__ __launch_bounds__(256) void gemm_mfma(
    const unsigned short* __restrict__ xb, const int* __restrict__ srcp,
    const float* __restrict__ etp, const float* __restrict__ freqs,
    const float* __restrict__ lw, const float* __restrict__ lb,
    const float* __restrict__ attn,
    unsigned short* __restrict__ h_p, float* __restrict__ alpha_p,
    int E, int n_tiles)
{
    __shared__ unsigned short te[2][TM * 64];   // 16 KB, swizzled
    __shared__ float apart[2][4][TM];           // 2 KB

    const int tid  = threadIdx.x;
    const int lane = tid & 63;
    const int wv   = tid >> 6;          // wave 0..3 (= te freq block)
    const int c16  = lane & 15;
    const int g    = lane >> 4;         // 0..3
    const int wbase = wv * 32;          // this wave's channel base

    // W fragments in registers: lane's row(ch) = wbase+nf*16+c16; k = kk*32+g*8+j
    bf16x8 Wf[6][2];
    #pragma unroll
    for (int kk = 0; kk < 6; ++kk)
        #pragma unroll
        for (int nf = 0; nf < 2; ++nf) {
            const float* wp = lw + (size_t)(wbase + nf * 16 + c16) * KD + kk * 32 + g * 8;
            float4 v0 = *(const float4*)wp;
            float4 v1 = *(const float4*)(wp + 4);
            bf16x8 b;
            b[0] = (__bf16)v0.x; b[1] = (__bf16)v0.y; b[2] = (__bf16)v0.z; b[3] = (__bf16)v0.w;
            b[4] = (__bf16)v1.x; b[5] = (__bf16)v1.y; b[6] = (__bf16)v1.z; b[7] = (__bf16)v1.w;
            Wf[kk][nf] = b;
        }

    f32x4 bias_v[2], attn_v[2];
    #pragma unroll
    for (int nf = 0; nf < 2; ++nf) {
        bias_v[nf] = *(const f32x4*)(lb   + wbase + nf * 16 + g * 4);
        attn_v[nf] = *(const f32x4*)(attn + wbase + nf * 16 + g * 4);
    }

    // this wave's 8 frequencies, pre-scaled by 2*pi (radians for __sinf)
    float frv[8];
    #pragma unroll
    for (int j = 0; j < 8; ++j) frv[j] = freqs[wv * 8 + j] * 6.283185307179586f;

    // meta prefetch registers
    int sv[4]; float ts;
    {
        int e0 = blockIdx.x * TM;
        #pragma unroll
        for (int mi = 0; mi < 4; ++mi) {
            int e = e0 + mi * 16 + c16;
            sv[mi] = srcp[e < E ? e : E - 1];
        }
        int el = e0 + lane;
        ts = etp[el < E ? el : E - 1];
    }

    int cur = 0;
    int prev_e0 = -1;
    const int sgr = lane & 7;   // row swizzle key

    for (int tile = blockIdx.x; tile < n_tiles; tile += gridDim.x) {
        const int e0 = tile * TM;

        // ---- stage te[cur]: row = lane, freq block = wv ----
        {
            float sj[8], cj[8];
            #pragma unroll
            for (int j = 0; j < 8; ++j) {
                float ang = ts * frv[j];
                sj[j] = __sinf(ang);
                cj[j] = __cosf(ang);
            }
            unsigned short* tr = &te[cur][lane * 64];
            int gs = (wv ^ sgr) * 8;
            int gc = ((wv + 4) ^ sgr) * 8;
            *(ushort4*)(tr + gs)     = (ushort4){ f2b(sj[0]), f2b(sj[1]), f2b(sj[2]), f2b(sj[3]) };
            *(ushort4*)(tr + gs + 4) = (ushort4){ f2b(sj[4]), f2b(sj[5]), f2b(sj[6]), f2b(sj[7]) };
            *(ushort4*)(tr + gc)     = (ushort4){ f2b(cj[0]), f2b(cj[1]), f2b(cj[2]), f2b(cj[3]) };
            *(ushort4*)(tr + gc + 4) = (ushort4){ f2b(cj[4]), f2b(cj[5]), f2b(cj[6]), f2b(cj[7]) };
        }

        // ---- prefetch next tile's meta ----
        int nsv[4]; float nts = 0.0f;
        int ntile = tile + gridDim.x;
        if (ntile < n_tiles) {
            int ne0 = ntile * TM;
            #pragma unroll
            for (int mi = 0; mi < 4; ++mi) {
                int e = ne0 + mi * 16 + c16;
                nsv[mi] = srcp[e < E ? e : E - 1];
            }
            int el = ne0 + lane;
            nts = etp[el < E ? el : E - 1];
        } else {
            #pragma unroll
            for (int mi = 0; mi < 4; ++mi) nsv[mi] = 0;
        }

        __syncthreads();

        // ---- pipelined alpha store for previous tile ----
        if (prev_e0 >= 0 && tid < TM) {
            int e = prev_e0 + tid;
            if (e < E)
                alpha_p[e] = apart[cur ^ 1][0][tid] + apart[cur ^ 1][1][tid]
                           + apart[cur ^ 1][2][tid] + apart[cur ^ 1][3][tid];
        }

        // ---- MFMA: per mi, 4 x-frags (global gather) + sin/cos frags (LDS) ----
        f32x4 acc[4][2];
        #pragma unroll
        for (int mi = 0; mi < 4; ++mi) {
            acc[mi][0] = (f32x4){0.f, 0.f, 0.f, 0.f};
            acc[mi][1] = (f32x4){0.f, 0.f, 0.f, 0.f};
        }

        #pragma unroll
        for (int mi = 0; mi < 4; ++mi) {
            const uint4* xr = (const uint4*)(xb + (size_t)sv[mi] * IN_CHN + g * 8);
            #pragma unroll
            for (int kk = 0; kk < 4; ++kk) {
                bf16x8 a = __builtin_bit_cast(bf16x8, xr[kk * 4]);
                acc[mi][0] = __builtin_amdgcn_mfma_f32_16x16x32_bf16(Wf[kk][0], a, acc[mi][0], 0, 0, 0);
                acc[mi][1] = __builtin_amdgcn_mfma_f32_16x16x32_bf16(Wf[kk][1], a, acc[mi][1], 0, 0, 0);
            }
            int r = mi * 16 + c16;
            const unsigned short* trow = &te[cur][r * 64];
            bf16x8 s8 = __builtin_bit_cast(bf16x8, *(const uint4*)(trow + ((g ^ (r & 7)) * 8)));
            bf16x8 c8 = __builtin_bit_cast(bf16x8, *(const uint4*)(trow + (((g + 4) ^ (r & 7)) * 8)));
            acc[mi][0] = __builtin_amdgcn_mfma_f32_16x16x32_bf16(Wf[4][0], s8, acc[mi][0], 0, 0, 0);
            acc[mi][1] = __builtin_amdgcn_mfma_f32_16x16x32_bf16(Wf[4][1], s8, acc[mi][1], 0, 0, 0);
            acc[mi][0] = __builtin_amdgcn_mfma_f32_16x16x32_bf16(Wf[5][0], c8, acc[mi][0], 0, 0, 0);
            acc[mi][1] = __builtin_amdgcn_mfma_f32_16x16x32_bf16(Wf[5][1], c8, acc[mi][1], 0, 0, 0);
        }

        // ---- epilogue: tanh, alpha partial, direct global h store ----
        #pragma unroll
        for (int mi = 0; mi < 4; ++mi) {
            int e = e0 + mi * 16 + c16;
            float p = 0.0f;
            ushort4 pv[2];
            #pragma unroll
            for (int nf = 0; nf < 2; ++nf) {
                f32x4 z = acc[mi][nf];
                #pragma unroll
                for (int r = 0; r < 4; ++r) {
                    float h = fast_tanh(z[r] + bias_v[nf][r]);
                    z[r] = h;
                    p = fmaf(h, attn_v[nf][r], p);
                }
                pv[nf] = (ushort4){ f2b(z[0]), f2b(z[1]), f2b(z[2]), f2b(z[3]) };
            }
            p += __shfl_xor(p, 16);
            p += __shfl_xor(p, 32);
            if (e < E) {
                unsigned short* hp = h_p + (size_t)e * OUT_CHN + wbase + g * 4;
                *(ushort4*)hp        = pv[0];
                *(ushort4*)(hp + 16) = pv[1];
            }
            if (g == 0) apart[cur][wv][mi * 16 + c16] = p;
        }

        prev_e0 = e0;
        #pragma unroll
        for (int mi = 0; mi < 4; ++mi) sv[mi] = nsv[mi];
        ts = nts;
        cur ^= 1;
    }

    // drain: last tile's alpha
    __syncthreads();
    if (prev_e0 >= 0 && tid < TM) {
        int e = prev_e0 + tid;
        if (e < E)
            alpha_p[e] = apart[cur ^ 1][0][tid] + apart[cur ^ 1][1][tid]
                       + apart[cur ^ 1][2][tid] + apart[cur ^ 1][3][tid];
    }
}

// ---------------- per-node aggregation (one wave per node) ----------------

__global__ __launch_bounds__(256) void agg(
    const unsigned short* __restrict__ h_p, const float* __restrict__ alpha_p,
    const int* __restrict__ offs, const int* __restrict__ deg,
    float* __restrict__ out, int Nn)
{
    int wid  = threadIdx.x >> 6;
    int lane = threadIdx.x & 63;
    int node = blockIdx.x * 4 + wid;
    if (node >= Nn) return;
    int start = offs[node];
    int d = deg[node];
    float* op = out + (size_t)node * OUT_CHN + lane * 2;
    if (d == 0) { op[0] = 0.0f; op[1] = 0.0f; return; }

    float m = -INFINITY;
    for (int i = lane; i < d; i += 64) m = fmaxf(m, alpha_p[start + i]);
    #pragma unroll
    for (int off = 32; off > 0; off >>= 1) m = fmaxf(m, __shfl_xor(m, off));

    float s = 0.0f;
    for (int i = lane; i < d; i += 64) s += __expf(alpha_p[start + i] - m);
    #pragma unroll
    for (int off = 32; off > 0; off >>= 1) s += __shfl_xor(s, off);
    float rs = __builtin_amdgcn_rcpf(s + 1e-16f);

    float a0 = 0.0f, a1 = 0.0f;
    for (int i = 0; i < d; ++i) {
        float w = __expf(alpha_p[start + i] - m) * rs;
        unsigned int hv = *(const unsigned int*)(h_p + (size_t)(start + i) * OUT_CHN + lane * 2);
        a0 = fmaf(b2f((unsigned short)(hv & 0xFFFFu)), w, a0);
        a1 = fmaf(b2f((unsigned short)(hv >> 16)), w, a1);
    }
    op[0] = a0; op[1] = a1;
}

// ---------------- launch ----------------

extern "C" void kernel_launch(void* const* d_in, const int* in_sizes, int n_in,
                              void* d_out, int out_size, void* d_ws, size_t ws_size,
                              hipStream_t stream) {
    const float* x     = (const float*)d_in[0];
    const int*   ei    = (const int*)d_in[1];     // [2, E]
    const float* et    = (const float*)d_in[2];
    const float* freqs = (const float*)d_in[3];
    const float* lw    = (const float*)d_in[4];   // [128, 192]
    const float* lb    = (const float*)d_in[5];
    const float* attn  = (const float*)d_in[6];
    float* out = (float*)d_out;

    const int E  = in_sizes[2];
    const int Nn = in_sizes[0] / IN_CHN;

    // workspace layout
    char* ws = (char*)d_ws;
    unsigned short* h_p = (unsigned short*)ws;                // E*128 bf16 (perm order)
    size_t off = (size_t)E * OUT_CHN * sizeof(unsigned short);
    float* alpha_p = (float*)(ws + off); off += (size_t)E * sizeof(float);
    int*   srcp    = (int*)(ws + off);   off += (size_t)E * sizeof(int);
    float* etp     = (float*)(ws + off); off += (size_t)E * sizeof(float);
    unsigned short* xb = (unsigned short*)(ws + off); off += (size_t)Nn * IN_CHN * sizeof(unsigned short);
    int*   deg     = (int*)(ws + off);   off += (size_t)Nn * sizeof(int);
    int*   offs    = (int*)(ws + off);   off += (size_t)Nn * sizeof(int);
    int*   cursor  = (int*)(ws + off);   off += (size_t)Nn * sizeof(int);
    int*   partial = (int*)(ws + off);

    const int nblk = (Nn + 255) / 256;
    const int eblk = (E + 255) / 256;

    long long n8 = (long long)Nn * IN_CHN / 8;
    cvt_x<<<(unsigned)((n8 + 255) / 256), 256, 0, stream>>>(x, xb, n8);

    hipMemsetAsync(deg, 0, (size_t)Nn * sizeof(int), stream);
    count_deg<<<eblk, 256, 0, stream>>>(ei, deg, E);
    scan_local<<<nblk, 256, 0, stream>>>(deg, offs, partial, Nn);
    scan_partial<<<1, 256, 0, stream>>>(partial, nblk);
    finalize_offs<<<nblk, 256, 0, stream>>>(offs, partial, cursor, Nn);
    fill_perm<<<eblk, 256, 0, stream>>>(ei, et, cursor, srcp, etp, E);

    const int n_tiles = (E + TM - 1) / TM;
    gemm_mfma<<<768, 256, 0, stream>>>(xb, srcp, etp, freqs, lw, lb, attn,
                                       h_p, alpha_p, E, n_tiles);

    agg<<<(Nn + 3) / 4, 256, 0, stream>>>(h_p, alpha_p, offs, deg, out, Nn);
}

// Round 6
// 267.052 us; speedup vs baseline: 1.3707x; 1.1644x over previous
//
#include <hip/hip_runtime.h>
#include <hip/hip_bf16.h>
#include <math.h>

#define IN_CHN 128
#define OUT_CHN 128
#define KD 192
#define TM 64                  // edges per tile

typedef __bf16 bf16x8 __attribute__((ext_vector_type(8)));
typedef float f32x4 __attribute__((ext_vector_type(4)));

static __device__ __forceinline__ unsigned short f2b(float f) {
    return __builtin_bit_cast(unsigned short, (__bf16)f);   // RNE
}
static __device__ __forceinline__ float b2f(unsigned short b) {
    return __uint_as_float(((unsigned int)b) << 16);
}
static __device__ __forceinline__ float fast_tanh(float x) {
    float e = __expf(2.0f * x);
    return 1.0f - 2.0f * __builtin_amdgcn_rcpf(e + 1.0f);
}

// async global->LDS, 16B per lane; LDS dest wave-uniform base + lane*16
#define GLL16(gsrc, ldst) \
    __builtin_amdgcn_global_load_lds( \
        (const __attribute__((address_space(1))) unsigned int*)(gsrc), \
        (__attribute__((address_space(3))) unsigned int*)(ldst), 16, 0, 0)

// ---------------- x -> bf16 pre-conversion ----------------

__global__ __launch_bounds__(256) void cvt_x(const float* __restrict__ x,
    unsigned short* __restrict__ xb, long long n8)
{
    long long i = (long long)blockIdx.x * 256 + threadIdx.x;
    if (i >= n8) return;
    const float4* src = (const float4*)(x + i * 8);
    float4 v0 = src[0], v1 = src[1];
    ushort4 p0 = { f2b(v0.x), f2b(v0.y), f2b(v0.z), f2b(v0.w) };
    ushort4 p1 = { f2b(v1.x), f2b(v1.y), f2b(v1.z), f2b(v1.w) };
    *(ushort4*)(xb + i * 8)     = p0;
    *(ushort4*)(xb + i * 8 + 4) = p1;
}

// ---------------- CSR build ----------------

__global__ __launch_bounds__(256) void count_deg(const int* __restrict__ ei,
                                                 int* __restrict__ deg, int E) {
    int e = blockIdx.x * 256 + threadIdx.x;
    if (e < E) atomicAdd(&deg[ei[E + e]], 1);
}

static __device__ __forceinline__ int wave_incl_scan(int v, int lane) {
    #pragma unroll
    for (int off = 1; off < 64; off <<= 1) {
        int t = __shfl_up(v, off);
        if (lane >= off) v += t;
    }
    return v;
}

__global__ __launch_bounds__(256) void scan_local(const int* __restrict__ deg,
    int* __restrict__ offs, int* __restrict__ partial, int Nn)
{
    __shared__ int wsum[4];
    int tid = threadIdx.x, lane = tid & 63, wid = tid >> 6;
    int i = blockIdx.x * 256 + tid;
    int v = (i < Nn) ? deg[i] : 0;
    int incl = wave_incl_scan(v, lane);
    if (lane == 63) wsum[wid] = incl;
    __syncthreads();
    int wpre = 0;
    for (int w = 0; w < wid; ++w) wpre += wsum[w];
    if (i < Nn) offs[i] = wpre + incl - v;
    if (tid == 255) partial[blockIdx.x] = wpre + incl;
}

__global__ __launch_bounds__(256) void scan_partial(int* __restrict__ partial, int nparts)
{
    __shared__ int wsum[4];
    int tid = threadIdx.x, lane = tid & 63, wid = tid >> 6;
    int v = (tid < nparts) ? partial[tid] : 0;
    int incl = wave_incl_scan(v, lane);
    if (lane == 63) wsum[wid] = incl;
    __syncthreads();
    int wpre = 0;
    for (int w = 0; w < wid; ++w) wpre += wsum[w];
    if (tid < nparts) partial[tid] = wpre + incl - v;
}

__global__ __launch_bounds__(256) void finalize_offs(int* __restrict__ offs,
    const int* __restrict__ partial, int* __restrict__ cursor, int Nn)
{
    int i = blockIdx.x * 256 + threadIdx.x;
    if (i < Nn) { int o = offs[i] + partial[i >> 8]; offs[i] = o; cursor[i] = o; }
}

// scatter (src, t) into CSR-permuted order as one 8B store
__global__ __launch_bounds__(256) void fill_perm(const int* __restrict__ ei,
    const float* __restrict__ et, int* __restrict__ cursor,
    uint2* __restrict__ mt, int E)
{
    int e = blockIdx.x * 256 + threadIdx.x;
    if (e < E) {
        int d = ei[E + e];
        int pos = atomicAdd(&cursor[d], 1);
        mt[pos] = make_uint2((unsigned)ei[e], __float_as_uint(et[e]));
    }
}

// ---------------- MFMA GEMM + alpha ----------------
// h = tanh([x[src], te(t)] @ W^T + b), alpha = h . attn, edges in CSR order.
// 4 waves/block; tile = 64 edges x 128 ch; W frags in registers; x tile
// staged via global_load_lds into double-buffered LDS with SOURCE-side
// granule swizzle (c ^ row&15) so ds_read_b128 is conflict-free; te computed
// cooperatively into swizzled dbuf LDS. One barrier/tile; gll issued
// post-barrier (race-safe), drained at next barrier -> latency hidden.

__device__ __forceinline__ void load_meta(const uint2* __restrict__ mt,
    int tile, int E, int wv, int g, int lane, int sv[4], float& tsv)
{
    int e0 = tile * TM;
    #pragma unroll
    for (int i = 0; i < 4; ++i) {
        int e = e0 + wv * 16 + i * 4 + g;
        sv[i] = (int)mt[e < E ? e : E - 1].x;
    }
    int el = e0 + lane;
    tsv = __uint_as_float(mt[el < E ? el : E - 1].y);
}

__global__ __launch_bounds__(256) void gemm_mfma(
    const unsigned short* __restrict__ xb, const uint2* __restrict__ mt,
    const float* __restrict__ freqs, const float* __restrict__ lw,
    const float* __restrict__ lb, const float* __restrict__ attn,
    unsigned short* __restrict__ h_p, float* __restrict__ alpha_p,
    int E, int n_tiles)
{
    __shared__ unsigned short xs[2][TM][128];   // 32 KB x tile (dbuf)
    __shared__ unsigned short te[2][TM * 64];   // 16 KB te tile (dbuf, swizzled)
    __shared__ float apart[2][4][TM];           //  2 KB alpha partials

    const int tid  = threadIdx.x;
    const int lane = tid & 63;
    const int wv   = tid >> 6;          // wave 0..3 (= te freq block)
    const int c16  = lane & 15;
    const int g    = lane >> 4;         // 0..3
    const int wbase = wv * 32;          // this wave's channel base
    const int sgr  = lane & 7;          // te row swizzle key

    // W frags in registers: lane's row(ch) = wbase+nf*16+c16; k = kk*32+g*8+j
    bf16x8 Wf[6][2];
    #pragma unroll
    for (int kk = 0; kk < 6; ++kk)
        #pragma unroll
        for (int nf = 0; nf < 2; ++nf) {
            const float* wp = lw + (size_t)(wbase + nf * 16 + c16) * KD + kk * 32 + g * 8;
            float4 v0 = *(const float4*)wp;
            float4 v1 = *(const float4*)(wp + 4);
            bf16x8 b;
            b[0] = (__bf16)v0.x; b[1] = (__bf16)v0.y; b[2] = (__bf16)v0.z; b[3] = (__bf16)v0.w;
            b[4] = (__bf16)v1.x; b[5] = (__bf16)v1.y; b[6] = (__bf16)v1.z; b[7] = (__bf16)v1.w;
            Wf[kk][nf] = b;
        }

    f32x4 bias_v[2], attn_v[2];
    #pragma unroll
    for (int nf = 0; nf < 2; ++nf) {
        bias_v[nf] = *(const f32x4*)(lb   + wbase + nf * 16 + g * 4);
        attn_v[nf] = *(const f32x4*)(attn + wbase + nf * 16 + g * 4);
    }

    // this wave's 8 frequencies, pre-scaled by 2*pi
    float frv[8];
    #pragma unroll
    for (int j = 0; j < 8; ++j) frv[j] = freqs[wv * 8 + j] * 6.283185307179586f;

    const int stride = gridDim.x;
    float ts_cur, ts_nxt;
    int sv_nxt[4];

    // ---- prologue: meta(t0), gll(t0) -> xs[0], meta(t0+stride) ----
    {
        int sv0[4];
        load_meta(mt, blockIdx.x, E, wv, g, lane, sv0, ts_cur);
        #pragma unroll
        for (int i = 0; i < 4; ++i) {
            const int rlo = i * 4 + g;                 // row & 15
            const unsigned short* gsrc = xb + (size_t)sv0[i] * IN_CHN + ((c16 ^ rlo) * 8);
            GLL16(gsrc, &xs[0][wv * 16 + i * 4][0]);
        }
        int t1 = blockIdx.x + stride;
        load_meta(mt, t1 < n_tiles ? t1 : n_tiles - 1, E, wv, g, lane, sv_nxt, ts_nxt);
    }

    int cur = 0;
    int prev_e0 = -1;

    for (int tile = blockIdx.x; tile < n_tiles; tile += stride) {
        const int e0 = tile * TM;

        // ---- prefetch meta(t+2) ----
        int sv2[4]; float ts2;
        {
            int t2 = tile + 2 * stride;
            load_meta(mt, t2 < n_tiles ? t2 : n_tiles - 1, E, wv, g, lane, sv2, ts2);
        }

        // ---- stage te[cur]: row = lane, freq block = wv (dbuf-safe pre-barrier) ----
        {
            float sj[8], cj[8];
            #pragma unroll
            for (int j = 0; j < 8; ++j) {
                float ang = ts_cur * frv[j];
                sj[j] = __sinf(ang);
                cj[j] = __cosf(ang);
            }
            unsigned short* tr = &te[cur][lane * 64];
            int gs = (wv ^ sgr) * 8;
            int gc = ((wv + 4) ^ sgr) * 8;
            *(ushort4*)(tr + gs)     = (ushort4){ f2b(sj[0]), f2b(sj[1]), f2b(sj[2]), f2b(sj[3]) };
            *(ushort4*)(tr + gs + 4) = (ushort4){ f2b(sj[4]), f2b(sj[5]), f2b(sj[6]), f2b(sj[7]) };
            *(ushort4*)(tr + gc)     = (ushort4){ f2b(cj[0]), f2b(cj[1]), f2b(cj[2]), f2b(cj[3]) };
            *(ushort4*)(tr + gc + 4) = (ushort4){ f2b(cj[4]), f2b(cj[5]), f2b(cj[6]), f2b(cj[7]) };
        }

        __syncthreads();   // drains gll(t) + te writes; all waves past tile t-1 reads

        // ---- issue gll(t+1) -> xs[cur^1] (post-barrier: dbuf race-safe) ----
        if (tile + stride < n_tiles) {
            #pragma unroll
            for (int i = 0; i < 4; ++i) {
                const int rlo = i * 4 + g;
                const unsigned short* gsrc = xb + (size_t)sv_nxt[i] * IN_CHN + ((c16 ^ rlo) * 8);
                GLL16(gsrc, &xs[cur ^ 1][wv * 16 + i * 4][0]);
            }
        }

        // ---- pipelined alpha store for previous tile ----
        if (prev_e0 >= 0 && tid < TM) {
            int e = prev_e0 + tid;
            if (e < E)
                alpha_p[e] = apart[cur ^ 1][0][tid] + apart[cur ^ 1][1][tid]
                           + apart[cur ^ 1][2][tid] + apart[cur ^ 1][3][tid];
        }

        // ---- MFMA: x frags from swizzled LDS, te frags from LDS ----
        f32x4 acc[4][2];
        #pragma unroll
        for (int mi = 0; mi < 4; ++mi) {
            acc[mi][0] = (f32x4){0.f, 0.f, 0.f, 0.f};
            acc[mi][1] = (f32x4){0.f, 0.f, 0.f, 0.f};
        }

        const unsigned short* xsc = &xs[cur][0][0];
        const unsigned short* tec = &te[cur][0];
        #pragma unroll
        for (int mi = 0; mi < 4; ++mi) {
            const int r = mi * 16 + c16;
            const unsigned short* xrow = xsc + r * 128;
            #pragma unroll
            for (int kk = 0; kk < 4; ++kk) {
                const int slot = ((kk << 2) + g) ^ c16;   // source-swizzled granule
                bf16x8 a = __builtin_bit_cast(bf16x8, *(const uint4*)(xrow + slot * 8));
                acc[mi][0] = __builtin_amdgcn_mfma_f32_16x16x32_bf16(Wf[kk][0], a, acc[mi][0], 0, 0, 0);
                acc[mi][1] = __builtin_amdgcn_mfma_f32_16x16x32_bf16(Wf[kk][1], a, acc[mi][1], 0, 0, 0);
            }
            const unsigned short* trow = tec + r * 64;
            bf16x8 s8 = __builtin_bit_cast(bf16x8, *(const uint4*)(trow + ((g ^ (r & 7)) * 8)));
            bf16x8 c8 = __builtin_bit_cast(bf16x8, *(const uint4*)(trow + (((g + 4) ^ (r & 7)) * 8)));
            acc[mi][0] = __builtin_amdgcn_mfma_f32_16x16x32_bf16(Wf[4][0], s8, acc[mi][0], 0, 0, 0);
            acc[mi][1] = __builtin_amdgcn_mfma_f32_16x16x32_bf16(Wf[4][1], s8, acc[mi][1], 0, 0, 0);
            acc[mi][0] = __builtin_amdgcn_mfma_f32_16x16x32_bf16(Wf[5][0], c8, acc[mi][0], 0, 0, 0);
            acc[mi][1] = __builtin_amdgcn_mfma_f32_16x16x32_bf16(Wf[5][1], c8, acc[mi][1], 0, 0, 0);
        }

        // ---- epilogue: tanh, alpha partial, direct global h store ----
        #pragma unroll
        for (int mi = 0; mi < 4; ++mi) {
            int e = e0 + mi * 16 + c16;
            float p = 0.0f;
            ushort4 pv[2];
            #pragma unroll
            for (int nf = 0; nf < 2; ++nf) {
                f32x4 z = acc[mi][nf];
                #pragma unroll
                for (int r = 0; r < 4; ++r) {
                    float h = fast_tanh(z[r] + bias_v[nf][r]);
                    z[r] = h;
                    p = fmaf(h, attn_v[nf][r], p);
                }
                pv[nf] = (ushort4){ f2b(z[0]), f2b(z[1]), f2b(z[2]), f2b(z[3]) };
            }
            p += __shfl_xor(p, 16);
            p += __shfl_xor(p, 32);
            if (e < E) {
                unsigned short* hp = h_p + (size_t)e * OUT_CHN + wbase + g * 4;
                *(ushort4*)hp        = pv[0];
                *(ushort4*)(hp + 16) = pv[1];
            }
            if (g == 0) apart[cur][wv][mi * 16 + c16] = p;
        }

        prev_e0 = e0;
        ts_cur = ts_nxt; ts_nxt = ts2;
        #pragma unroll
        for (int i = 0; i < 4; ++i) sv_nxt[i] = sv2[i];
        cur ^= 1;
    }

    // drain: last tile's alpha
    __syncthreads();
    if (prev_e0 >= 0 && tid < TM) {
        int e = prev_e0 + tid;
        if (e < E)
            alpha_p[e] = apart[cur ^ 1][0][tid] + apart[cur ^ 1][1][tid]
                       + apart[cur ^ 1][2][tid] + apart[cur ^ 1][3][tid];
    }
}

// ---------------- per-node aggregation (one wave per node) ----------------
// pass 2: 4 edges/iter; lane = (sub: edge subgroup, 8 channels)

__global__ __launch_bounds__(256) void agg(
    const unsigned short* __restrict__ h_p, const float* __restrict__ alpha_p,
    const int* __restrict__ offs, const int* __restrict__ deg,
    float* __restrict__ out, int Nn)
{
    int wid  = threadIdx.x >> 6;
    int lane = threadIdx.x & 63;
    int node = blockIdx.x * 4 + wid;
    if (node >= Nn) return;
    int start = offs[node];
    int d = deg[node];
    int sub = lane >> 4;            // 0..3
    int ch  = (lane & 15) * 8;      // 8 channels per lane
    float4* op = (float4*)(out + (size_t)node * OUT_CHN + ch);
    if (d == 0) {
        if (sub == 0) { op[0] = (float4){0,0,0,0}; op[1] = (float4){0,0,0,0}; }
        return;
    }

    float m = -INFINITY;
    for (int i = lane; i < d; i += 64) m = fmaxf(m, alpha_p[start + i]);
    #pragma unroll
    for (int off = 32; off > 0; off >>= 1) m = fmaxf(m, __shfl_xor(m, off));

    float s = 0.0f;
    for (int i = lane; i < d; i += 64) s += __expf(alpha_p[start + i] - m);
    #pragma unroll
    for (int off = 32; off > 0; off >>= 1) s += __shfl_xor(s, off);
    float rs = __builtin_amdgcn_rcpf(s + 1e-16f);

    float a[8];
    #pragma unroll
    for (int q = 0; q < 8; ++q) a[q] = 0.0f;

    for (int i = 0; i < d; i += 4) {
        int idx = i + sub;
        float w = 0.0f;
        uint4 hv = {0u, 0u, 0u, 0u};
        if (idx < d) {
            w = __expf(alpha_p[start + idx] - m) * rs;
            hv = *(const uint4*)(h_p + (size_t)(start + idx) * OUT_CHN + ch);
        }
        unsigned int hw[4] = { hv.x, hv.y, hv.z, hv.w };
        #pragma unroll
        for (int q = 0; q < 4; ++q) {
            a[2*q]   = fmaf(b2f((unsigned short)(hw[q] & 0xFFFFu)), w, a[2*q]);
            a[2*q+1] = fmaf(b2f((unsigned short)(hw[q] >> 16)),     w, a[2*q+1]);
        }
    }
    #pragma unroll
    for (int q = 0; q < 8; ++q) {
        a[q] += __shfl_xor(a[q], 16);
        a[q] += __shfl_xor(a[q], 32);
    }
    if (sub == 0) {
        op[0] = (float4){a[0], a[1], a[2], a[3]};
        op[1] = (float4){a[4], a[5], a[6], a[7]};
    }
}

// ---------------- launch ----------------

extern "C" void kernel_launch(void* const* d_in, const int* in_sizes, int n_in,
                              void* d_out, int out_size, void* d_ws, size_t ws_size,
                              hipStream_t stream) {
    const float* x     = (const float*)d_in[0];
    const int*   ei    = (const int*)d_in[1];     // [2, E]
    const float* et    = (const float*)d_in[2];
    const float* freqs = (const float*)d_in[3];
    const float* lw    = (const float*)d_in[4];   // [128, 192]
    const float* lb    = (const float*)d_in[5];
    const float* attn  = (const float*)d_in[6];
    float* out = (float*)d_out;

    const int E  = in_sizes[2];
    const int Nn = in_sizes[0] / IN_CHN;

    // workspace layout
    char* ws = (char*)d_ws;
    unsigned short* h_p = (unsigned short*)ws;                // E*128 bf16 (perm order)
    size_t off = (size_t)E * OUT_CHN * sizeof(unsigned short);
    float* alpha_p = (float*)(ws + off); off += (size_t)E * sizeof(float);
    uint2* mt      = (uint2*)(ws + off); off += (size_t)E * sizeof(uint2);
    unsigned short* xb = (unsigned short*)(ws + off); off += (size_t)Nn * IN_CHN * sizeof(unsigned short);
    int*   deg     = (int*)(ws + off);   off += (size_t)Nn * sizeof(int);
    int*   offs    = (int*)(ws + off);   off += (size_t)Nn * sizeof(int);
    int*   cursor  = (int*)(ws + off);   off += (size_t)Nn * sizeof(int);
    int*   partial = (int*)(ws + off);

    const int nblk = (Nn + 255) / 256;
    const int eblk = (E + 255) / 256;

    long long n8 = (long long)Nn * IN_CHN / 8;
    cvt_x<<<(unsigned)((n8 + 255) / 256), 256, 0, stream>>>(x, xb, n8);

    hipMemsetAsync(deg, 0, (size_t)Nn * sizeof(int), stream);
    count_deg<<<eblk, 256, 0, stream>>>(ei, deg, E);
    scan_local<<<nblk, 256, 0, stream>>>(deg, offs, partial, Nn);
    scan_partial<<<1, 256, 0, stream>>>(partial, nblk);
    finalize_offs<<<nblk, 256, 0, stream>>>(offs, partial, cursor, Nn);
    fill_perm<<<eblk, 256, 0, stream>>>(ei, et, cursor, mt, E);

    const int n_tiles = (E + TM - 1) / TM;
    gemm_mfma<<<768, 256, 0, stream>>>(xb, mt, freqs, lw, lb, attn,
                                       h_p, alpha_p, E, n_tiles);

    agg<<<(Nn + 3) / 4, 256, 0, stream>>>(h_p, alpha_p, offs, deg, out, Nn);
}

// Round 7
// 250.830 us; speedup vs baseline: 1.4594x; 1.0647x over previous
//
#include <hip/hip_runtime.h>
#include <hip/hip_bf16.h>
#include <math.h>

#define IN_CHN 128
#define OUT_CHN 128
#define KD 192
#define TM 64                  // edges per tile

typedef __bf16 bf16x8 __attribute__((ext_vector_type(8)));
typedef float f32x4 __attribute__((ext_vector_type(4)));

static __device__ __forceinline__ unsigned short f2b(float f) {
    return __builtin_bit_cast(unsigned short, (__bf16)f);   // RNE
}
static __device__ __forceinline__ float b2f(unsigned short b) {
    return __uint_as_float(((unsigned int)b) << 16);
}
static __device__ __forceinline__ float fast_tanh(float x) {
    float e = __expf(2.0f * x);
    return 1.0f - 2.0f * __builtin_amdgcn_rcpf(e + 1.0f);
}

// async global->LDS, 16B per lane; LDS dest wave-uniform base + lane*16
#define GLL16(gsrc, ldst) \
    __builtin_amdgcn_global_load_lds( \
        (const __attribute__((address_space(1))) unsigned int*)(gsrc), \
        (__attribute__((address_space(3))) unsigned int*)(ldst), 16, 0, 0)

// light barrier: cross-wave LDS visibility WITHOUT draining vmcnt (keeps
// in-flight global_load_lds alive across it)
#define LDS_BARRIER() do { \
    asm volatile("s_waitcnt lgkmcnt(0)" ::: "memory"); \
    __builtin_amdgcn_s_barrier(); \
    __builtin_amdgcn_sched_barrier(0); \
} while (0)

// ---------------- x -> bf16 pre-conversion ----------------

__global__ __launch_bounds__(256) void cvt_x(const float* __restrict__ x,
    unsigned short* __restrict__ xb, long long n8)
{
    long long i = (long long)blockIdx.x * 256 + threadIdx.x;
    if (i >= n8) return;
    const float4* src = (const float4*)(x + i * 8);
    float4 v0 = src[0], v1 = src[1];
    ushort4 p0 = { f2b(v0.x), f2b(v0.y), f2b(v0.z), f2b(v0.w) };
    ushort4 p1 = { f2b(v1.x), f2b(v1.y), f2b(v1.z), f2b(v1.w) };
    *(ushort4*)(xb + i * 8)     = p0;
    *(ushort4*)(xb + i * 8 + 4) = p1;
}

// ---------------- CSR build ----------------

__global__ __launch_bounds__(256) void count_deg(const int* __restrict__ ei,
                                                 int* __restrict__ deg, int E) {
    int e = blockIdx.x * 256 + threadIdx.x;
    if (e < E) atomicAdd(&deg[ei[E + e]], 1);
}

static __device__ __forceinline__ int wave_incl_scan(int v, int lane) {
    #pragma unroll
    for (int off = 1; off < 64; off <<= 1) {
        int t = __shfl_up(v, off);
        if (lane >= off) v += t;
    }
    return v;
}

__global__ __launch_bounds__(256) void scan_local(const int* __restrict__ deg,
    int* __restrict__ offs, int* __restrict__ partial, int Nn)
{
    __shared__ int wsum[4];
    int tid = threadIdx.x, lane = tid & 63, wid = tid >> 6;
    int i = blockIdx.x * 256 + tid;
    int v = (i < Nn) ? deg[i] : 0;
    int incl = wave_incl_scan(v, lane);
    if (lane == 63) wsum[wid] = incl;
    __syncthreads();
    int wpre = 0;
    for (int w = 0; w < wid; ++w) wpre += wsum[w];
    if (i < Nn) offs[i] = wpre + incl - v;
    if (tid == 255) partial[blockIdx.x] = wpre + incl;
}

__global__ __launch_bounds__(256) void scan_partial(int* __restrict__ partial, int nparts)
{
    __shared__ int wsum[4];
    int tid = threadIdx.x, lane = tid & 63, wid = tid >> 6;
    int v = (tid < nparts) ? partial[tid] : 0;
    int incl = wave_incl_scan(v, lane);
    if (lane == 63) wsum[wid] = incl;
    __syncthreads();
    int wpre = 0;
    for (int w = 0; w < wid; ++w) wpre += wsum[w];
    if (tid < nparts) partial[tid] = wpre + incl - v;
}

__global__ __launch_bounds__(256) void finalize_offs(int* __restrict__ offs,
    const int* __restrict__ partial, int* __restrict__ cursor, int Nn)
{
    int i = blockIdx.x * 256 + threadIdx.x;
    if (i < Nn) { int o = offs[i] + partial[i >> 8]; offs[i] = o; cursor[i] = o; }
}

// scatter (src, t) into CSR-permuted order as one 8B store
__global__ __launch_bounds__(256) void fill_perm(const int* __restrict__ ei,
    const float* __restrict__ et, int* __restrict__ cursor,
    uint2* __restrict__ mt, int E)
{
    int e = blockIdx.x * 256 + threadIdx.x;
    if (e < E) {
        int d = ei[E + e];
        int pos = atomicAdd(&cursor[d], 1);
        mt[pos] = make_uint2((unsigned)ei[e], __float_as_uint(et[e]));
    }
}

// ---------------- MFMA GEMM + alpha ----------------
// h = tanh([x[src], te(t)] @ W^T + b), alpha = h . attn, edges in CSR order.
// 4 waves/block; tile = 64 edges x 128 ch; W frags in registers; x tile via
// global_load_lds into dbuf LDS (source-side granule swizzle c^row&15);
// te single-buffered (written post-A, consumed post-light-B); alpha wave
// partials stored to global alpha4[4][E], reduced by sum_alpha.
// LDS = 32K (xs) + 8K (te) = 40960 B -> 4 blocks/CU.

__device__ __forceinline__ void load_meta(const uint2* __restrict__ mt,
    int tile, int E, int wv, int g, int lane, int sv[4], float& tsv)
{
    int e0 = tile * TM;
    #pragma unroll
    for (int i = 0; i < 4; ++i) {
        int e = e0 + wv * 16 + i * 4 + g;
        sv[i] = (int)mt[e < E ? e : E - 1].x;
    }
    int el = e0 + lane;
    tsv = __uint_as_float(mt[el < E ? el : E - 1].y);
}

__global__ __launch_bounds__(256) void gemm_mfma(
    const unsigned short* __restrict__ xb, const uint2* __restrict__ mt,
    const float* __restrict__ freqs, const float* __restrict__ lw,
    const float* __restrict__ lb, const float* __restrict__ attn,
    unsigned short* __restrict__ h_p, float* __restrict__ alpha4,
    int E, int Ep, int n_tiles)
{
    __shared__ unsigned short xs[2][TM][128];   // 32 KB x tile (dbuf)
    __shared__ unsigned short te[TM * 64];      //  8 KB te tile (single, swizzled)

    const int tid  = threadIdx.x;
    const int lane = tid & 63;
    const int wv   = tid >> 6;          // wave 0..3 (= te freq block)
    const int c16  = lane & 15;
    const int g    = lane >> 4;         // 0..3
    const int wbase = wv * 32;          // this wave's channel base
    const int sgr  = lane & 7;          // te row swizzle key

    // W frags in registers: lane's row(ch) = wbase+nf*16+c16; k = kk*32+g*8+j
    bf16x8 Wf[6][2];
    #pragma unroll
    for (int kk = 0; kk < 6; ++kk)
        #pragma unroll
        for (int nf = 0; nf < 2; ++nf) {
            const float* wp = lw + (size_t)(wbase + nf * 16 + c16) * KD + kk * 32 + g * 8;
            float4 v0 = *(const float4*)wp;
            float4 v1 = *(const float4*)(wp + 4);
            bf16x8 b;
            b[0] = (__bf16)v0.x; b[1] = (__bf16)v0.y; b[2] = (__bf16)v0.z; b[3] = (__bf16)v0.w;
            b[4] = (__bf16)v1.x; b[5] = (__bf16)v1.y; b[6] = (__bf16)v1.z; b[7] = (__bf16)v1.w;
            Wf[kk][nf] = b;
        }

    f32x4 bias_v[2], attn_v[2];
    #pragma unroll
    for (int nf = 0; nf < 2; ++nf) {
        bias_v[nf] = *(const f32x4*)(lb   + wbase + nf * 16 + g * 4);
        attn_v[nf] = *(const f32x4*)(attn + wbase + nf * 16 + g * 4);
    }

    // this wave's 8 frequencies, pre-scaled by 2*pi
    float frv[8];
    #pragma unroll
    for (int j = 0; j < 8; ++j) frv[j] = freqs[wv * 8 + j] * 6.283185307179586f;

    const int stride = gridDim.x;
    float ts_cur, ts_nxt;
    int sv_nxt[4];

    // ---- prologue: meta(t0), gll(t0) -> xs[0], meta(t1) ----
    {
        int sv0[4];
        load_meta(mt, blockIdx.x, E, wv, g, lane, sv0, ts_cur);
        #pragma unroll
        for (int i = 0; i < 4; ++i) {
            const int rlo = i * 4 + g;                 // row & 15
            const unsigned short* gsrc = xb + (size_t)sv0[i] * IN_CHN + ((c16 ^ rlo) * 8);
            GLL16(gsrc, &xs[0][wv * 16 + i * 4][0]);
        }
        int t1 = blockIdx.x + stride;
        load_meta(mt, t1 < n_tiles ? t1 : n_tiles - 1, E, wv, g, lane, sv_nxt, ts_nxt);
    }

    int cur = 0;

    for (int tile = blockIdx.x; tile < n_tiles; tile += stride) {
        const int e0 = tile * TM;

        // ---- compute te(t) packs in registers (overlaps gll(t) drain) ----
        ushort4 tp[4];
        {
            float sj[8], cj[8];
            #pragma unroll
            for (int j = 0; j < 8; ++j) {
                float ang = ts_cur * frv[j];
                sj[j] = __sinf(ang);
                cj[j] = __cosf(ang);
            }
            tp[0] = (ushort4){ f2b(sj[0]), f2b(sj[1]), f2b(sj[2]), f2b(sj[3]) };
            tp[1] = (ushort4){ f2b(sj[4]), f2b(sj[5]), f2b(sj[6]), f2b(sj[7]) };
            tp[2] = (ushort4){ f2b(cj[0]), f2b(cj[1]), f2b(cj[2]), f2b(cj[3]) };
            tp[3] = (ushort4){ f2b(cj[4]), f2b(cj[5]), f2b(cj[6]), f2b(cj[7]) };
        }

        // ---- prefetch meta(t+2) ----
        int sv2[4]; float ts2;
        {
            int t2 = tile + 2 * stride;
            load_meta(mt, t2 < n_tiles ? t2 : n_tiles - 1, E, wv, g, lane, sv2, ts2);
        }

        __syncthreads();   // A: drains gll(t); all waves done reading xs[cur^1], te(t-1)

        // ---- issue gll(t+1) -> xs[cur^1] (stays in flight through light-B) ----
        if (tile + stride < n_tiles) {
            #pragma unroll
            for (int i = 0; i < 4; ++i) {
                const int rlo = i * 4 + g;
                const unsigned short* gsrc = xb + (size_t)sv_nxt[i] * IN_CHN + ((c16 ^ rlo) * 8);
                GLL16(gsrc, &xs[cur ^ 1][wv * 16 + i * 4][0]);
            }
        }

        // ---- write te(t): row = lane, freq block = wv, granule-swizzled ----
        {
            unsigned short* tr = &te[lane * 64];
            int gs = (wv ^ sgr) * 8;
            int gc = ((wv + 4) ^ sgr) * 8;
            *(ushort4*)(tr + gs)     = tp[0];
            *(ushort4*)(tr + gs + 4) = tp[1];
            *(ushort4*)(tr + gc)     = tp[2];
            *(ushort4*)(tr + gc + 4) = tp[3];
        }

        LDS_BARRIER();     // B: te visible; gll(t+1) still in flight

        // ---- MFMA: x frags from swizzled LDS, te frags from LDS ----
        f32x4 acc[4][2];
        #pragma unroll
        for (int mi = 0; mi < 4; ++mi) {
            acc[mi][0] = (f32x4){0.f, 0.f, 0.f, 0.f};
            acc[mi][1] = (f32x4){0.f, 0.f, 0.f, 0.f};
        }

        const unsigned short* xsc = &xs[cur][0][0];
        #pragma unroll
        for (int mi = 0; mi < 4; ++mi) {
            const int r = mi * 16 + c16;
            const unsigned short* xrow = xsc + r * 128;
            #pragma unroll
            for (int kk = 0; kk < 4; ++kk) {
                const int slot = ((kk << 2) + g) ^ c16;   // source-swizzled granule
                bf16x8 a = __builtin_bit_cast(bf16x8, *(const uint4*)(xrow + slot * 8));
                acc[mi][0] = __builtin_amdgcn_mfma_f32_16x16x32_bf16(Wf[kk][0], a, acc[mi][0], 0, 0, 0);
                acc[mi][1] = __builtin_amdgcn_mfma_f32_16x16x32_bf16(Wf[kk][1], a, acc[mi][1], 0, 0, 0);
            }
            const unsigned short* trow = &te[r * 64];
            bf16x8 s8 = __builtin_bit_cast(bf16x8, *(const uint4*)(trow + ((g ^ (r & 7)) * 8)));
            bf16x8 c8 = __builtin_bit_cast(bf16x8, *(const uint4*)(trow + (((g + 4) ^ (r & 7)) * 8)));
            acc[mi][0] = __builtin_amdgcn_mfma_f32_16x16x32_bf16(Wf[4][0], s8, acc[mi][0], 0, 0, 0);
            acc[mi][1] = __builtin_amdgcn_mfma_f32_16x16x32_bf16(Wf[4][1], s8, acc[mi][1], 0, 0, 0);
            acc[mi][0] = __builtin_amdgcn_mfma_f32_16x16x32_bf16(Wf[5][0], c8, acc[mi][0], 0, 0, 0);
            acc[mi][1] = __builtin_amdgcn_mfma_f32_16x16x32_bf16(Wf[5][1], c8, acc[mi][1], 0, 0, 0);
        }

        // ---- epilogue: tanh, alpha partial, direct global stores ----
        #pragma unroll
        for (int mi = 0; mi < 4; ++mi) {
            int e = e0 + mi * 16 + c16;
            float p = 0.0f;
            ushort4 pv[2];
            #pragma unroll
            for (int nf = 0; nf < 2; ++nf) {
                f32x4 z = acc[mi][nf];
                #pragma unroll
                for (int r = 0; r < 4; ++r) {
                    float h = fast_tanh(z[r] + bias_v[nf][r]);
                    z[r] = h;
                    p = fmaf(h, attn_v[nf][r], p);
                }
                pv[nf] = (ushort4){ f2b(z[0]), f2b(z[1]), f2b(z[2]), f2b(z[3]) };
            }
            p += __shfl_xor(p, 16);
            p += __shfl_xor(p, 32);
            if (e < E) {
                unsigned short* hp = h_p + (size_t)e * OUT_CHN + wbase + g * 4;
                *(ushort4*)hp        = pv[0];
                *(ushort4*)(hp + 16) = pv[1];
                if (g == 0) alpha4[(size_t)wv * Ep + e] = p;
            }
        }

        ts_cur = ts_nxt; ts_nxt = ts2;
        #pragma unroll
        for (int i = 0; i < 4; ++i) sv_nxt[i] = sv2[i];
        cur ^= 1;
    }
}

// ---------------- alpha4 plane reduce ----------------

__global__ __launch_bounds__(256) void sum_alpha(const float* __restrict__ a4,
    float* __restrict__ ap, int E, int Ep)
{
    int i = blockIdx.x * 256 + threadIdx.x;   // float4 index
    int e = i * 4;
    if (e + 3 < E) {
        float4 v0 = *(const float4*)(a4 + e);
        float4 v1 = *(const float4*)(a4 + Ep + e);
        float4 v2 = *(const float4*)(a4 + 2 * (size_t)Ep + e);
        float4 v3 = *(const float4*)(a4 + 3 * (size_t)Ep + e);
        float4 r = { v0.x + v1.x + v2.x + v3.x, v0.y + v1.y + v2.y + v3.y,
                     v0.z + v1.z + v2.z + v3.z, v0.w + v1.w + v2.w + v3.w };
        *(float4*)(ap + e) = r;
    } else {
        for (int q = e; q < E; ++q)
            ap[q] = a4[q] + a4[Ep + q] + a4[2 * (size_t)Ep + q] + a4[3 * (size_t)Ep + q];
    }
}

// ---------------- per-node aggregation (one wave per node) ----------------

__global__ __launch_bounds__(256) void agg(
    const unsigned short* __restrict__ h_p, const float* __restrict__ alpha_p,
    const int* __restrict__ offs, const int* __restrict__ deg,
    float* __restrict__ out, int Nn)
{
    int wid  = threadIdx.x >> 6;
    int lane = threadIdx.x & 63;
    int node = blockIdx.x * 4 + wid;
    if (node >= Nn) return;
    int start = offs[node];
    int d = deg[node];
    int sub = lane >> 4;            // 0..3
    int ch  = (lane & 15) * 8;      // 8 channels per lane
    float4* op = (float4*)(out + (size_t)node * OUT_CHN + ch);
    if (d == 0) {
        if (sub == 0) { op[0] = (float4){0,0,0,0}; op[1] = (float4){0,0,0,0}; }
        return;
    }

    float m = -INFINITY;
    for (int i = lane; i < d; i += 64) m = fmaxf(m, alpha_p[start + i]);
    #pragma unroll
    for (int off = 32; off > 0; off >>= 1) m = fmaxf(m, __shfl_xor(m, off));

    float s = 0.0f;
    for (int i = lane; i < d; i += 64) s += __expf(alpha_p[start + i] - m);
    #pragma unroll
    for (int off = 32; off > 0; off >>= 1) s += __shfl_xor(s, off);
    float rs = __builtin_amdgcn_rcpf(s + 1e-16f);

    float a[8];
    #pragma unroll
    for (int q = 0; q < 8; ++q) a[q] = 0.0f;

    for (int i = 0; i < d; i += 4) {
        int idx = i + sub;
        float w = 0.0f;
        uint4 hv = {0u, 0u, 0u, 0u};
        if (idx < d) {
            w = __expf(alpha_p[start + idx] - m) * rs;
            hv = *(const uint4*)(h_p + (size_t)(start + idx) * OUT_CHN + ch);
        }
        unsigned int hw[4] = { hv.x, hv.y, hv.z, hv.w };
        #pragma unroll
        for (int q = 0; q < 4; ++q) {
            a[2*q]   = fmaf(b2f((unsigned short)(hw[q] & 0xFFFFu)), w, a[2*q]);
            a[2*q+1] = fmaf(b2f((unsigned short)(hw[q] >> 16)),     w, a[2*q+1]);
        }
    }
    #pragma unroll
    for (int q = 0; q < 8; ++q) {
        a[q] += __shfl_xor(a[q], 16);
        a[q] += __shfl_xor(a[q], 32);
    }
    if (sub == 0) {
        op[0] = (float4){a[0], a[1], a[2], a[3]};
        op[1] = (float4){a[4], a[5], a[6], a[7]};
    }
}

// ---------------- launch ----------------

extern "C" void kernel_launch(void* const* d_in, const int* in_sizes, int n_in,
                              void* d_out, int out_size, void* d_ws, size_t ws_size,
                              hipStream_t stream) {
    const float* x     = (const float*)d_in[0];
    const int*   ei    = (const int*)d_in[1];     // [2, E]
    const float* et    = (const float*)d_in[2];
    const float* freqs = (const float*)d_in[3];
    const float* lw    = (const float*)d_in[4];   // [128, 192]
    const float* lb    = (const float*)d_in[5];
    const float* attn  = (const float*)d_in[6];
    float* out = (float*)d_out;

    const int E  = in_sizes[2];
    const int Nn = in_sizes[0] / IN_CHN;
    const int Ep = (E + 3) & ~3;

    // workspace layout
    char* ws = (char*)d_ws;
    unsigned short* h_p = (unsigned short*)ws;                // E*128 bf16 (perm order)
    size_t off = (size_t)E * OUT_CHN * sizeof(unsigned short);
    float* alpha_p = (float*)(ws + off); off += (size_t)Ep * sizeof(float);
    float* alpha4  = (float*)(ws + off); off += (size_t)Ep * 4 * sizeof(float);
    uint2* mt      = (uint2*)(ws + off); off += (size_t)E * sizeof(uint2);
    unsigned short* xb = (unsigned short*)(ws + off); off += (size_t)Nn * IN_CHN * sizeof(unsigned short);
    int*   deg     = (int*)(ws + off);   off += (size_t)Nn * sizeof(int);
    int*   offs    = (int*)(ws + off);   off += (size_t)Nn * sizeof(int);
    int*   cursor  = (int*)(ws + off);   off += (size_t)Nn * sizeof(int);
    int*   partial = (int*)(ws + off);

    const int nblk = (Nn + 255) / 256;
    const int eblk = (E + 255) / 256;

    long long n8 = (long long)Nn * IN_CHN / 8;
    cvt_x<<<(unsigned)((n8 + 255) / 256), 256, 0, stream>>>(x, xb, n8);

    hipMemsetAsync(deg, 0, (size_t)Nn * sizeof(int), stream);
    count_deg<<<eblk, 256, 0, stream>>>(ei, deg, E);
    scan_local<<<nblk, 256, 0, stream>>>(deg, offs, partial, Nn);
    scan_partial<<<1, 256, 0, stream>>>(partial, nblk);
    finalize_offs<<<nblk, 256, 0, stream>>>(offs, partial, cursor, Nn);
    fill_perm<<<eblk, 256, 0, stream>>>(ei, et, cursor, mt, E);

    const int n_tiles = (E + TM - 1) / TM;
    gemm_mfma<<<1024, 256, 0, stream>>>(xb, mt, freqs, lw, lb, attn,
                                        h_p, alpha4, E, Ep, n_tiles);

    sum_alpha<<<(Ep / 4 + 255) / 256, 256, 0, stream>>>(alpha4, alpha_p, E, Ep);

    agg<<<(Nn + 3) / 4, 256, 0, stream>>>(h_p, alpha_p, offs, deg, out, Nn);
}